// Round 2
// baseline (488.159 us; speedup 1.0000x reference)
//
#include <hip/hip_runtime.h>
#include <math.h>

#define N_NODES 524288
#define BATCH   4096
#define HID     128
#define MAXL    512    // max segment length bound (mean 128, sigma ~11; max ~175)

typedef __attribute__((ext_vector_type(8))) short bf16x8;
typedef __attribute__((ext_vector_type(4))) float f32x4;

__device__ __forceinline__ unsigned short f2bf(float f) {
  unsigned int u = __float_as_uint(f);
  u = (u + 0x7FFFu + ((u >> 16) & 1u)) >> 16;   // RNE
  return (unsigned short)u;
}

__device__ __forceinline__ float fast_tanh(float x) {
  // tanh via single v_exp + v_rcp; clamp so exp can't overflow. |err| < 1e-6.
  float cx = fminf(fmaxf(x, -9.f), 9.f);
  float e  = __expf(2.f * cx);
  return (e - 1.f) * __builtin_amdgcn_rcpf(e + 1.f);
}

// K0: segment boundaries from sorted ball_batch -> rs[0..BATCH], rs[b]=first idx of seg b
__global__ __launch_bounds__(256) void k_bounds(const int* __restrict__ bb,
                                                int* __restrict__ rs)
{
  const int i = blockIdx.x * 256 + threadIdx.x;
  if (i >= N_NODES) return;
  const int cur  = bb[i];
  const int prev = (i == 0) ? -1 : bb[i - 1];
  for (int b = prev + 1; b <= cur; ++b) rs[b] = i;
  if (i == N_NODES - 1)
    for (int b = cur + 1; b <= BATCH; ++b) rs[b] = N_NODES;
}

// K1: fused scores (bf16 MFMA MLP) -> softmax -> weighted pooling.
// 4 waves per segment. Phase A: n-split (wave w owns n-tile w, fb = 16 VGPRs).
// Phase B: softmax over combined partials in LDS. Phase C: 4-way row-split pool.
__global__ __launch_bounds__(256, 8) void k_score_pool(
    const float* __restrict__ ball, const int* __restrict__ rs,
    const float* __restrict__ w1, const float* __restrict__ b1,
    const float* __restrict__ w2, const float* __restrict__ b2,
    float* __restrict__ pooled)
{
  __shared__ float  s_part[4][MAXL];
  __shared__ float  s_red[4];
  __shared__ float4 s_red4[3][32];

  const int tid  = threadIdx.x;
  const int lane = tid & 63;
  const int wv   = tid >> 6;       // wave = n-tile index 0..3
  const int m16  = lane & 15;
  const int quad = lane >> 4;
  const int b    = blockIdx.x;

  const int start = rs[b];
  const int end   = rs[b + 1];
  int L = end - start;

  float4* outp = (float4*)(pooled + (size_t)b * HID);
  if (L <= 0) { if (tid < 32) outp[tid] = make_float4(0.f,0.f,0.f,0.f); return; }
  if (L > MAXL) L = MAXL;          // statistically unreachable

  // ---- W1 fragment for this wave's n-tile: n = wv*16+m16, k = s*32+quad*8+j ----
  bf16x8 fb[4];
  const int n = wv * 16 + m16;
  #pragma unroll
  for (int s = 0; s < 4; ++s) {
    const int k0 = s * 32 + quad * 8;
    bf16x8 v;
    #pragma unroll
    for (int j = 0; j < 8; ++j) v[j] = (short)f2bf(w1[(k0 + j) * 64 + n]);
    fb[s] = v;
  }
  const float b1v = b1[n], w2v = w2[n];

  // ---- Phase A: per-wave 16-col partial of tanh(x@W1+b1)@W2 for 16-row tiles ----
  for (int t0 = 0; t0 < L; t0 += 16) {
    int row = start + t0 + m16;
    if (row >= end) row = end - 1;               // pad rows; scores beyond L unused
    const float4* rp = (const float4*)(ball + (size_t)row * HID) + quad * 2;
    f32x4 acc = {0.f, 0.f, 0.f, 0.f};
    #pragma unroll
    for (int s = 0; s < 4; ++s) {
      float4 x0 = rp[s * 8], x1 = rp[s * 8 + 1];
      bf16x8 fa;
      fa[0]=(short)f2bf(x0.x); fa[1]=(short)f2bf(x0.y);
      fa[2]=(short)f2bf(x0.z); fa[3]=(short)f2bf(x0.w);
      fa[4]=(short)f2bf(x1.x); fa[5]=(short)f2bf(x1.y);
      fa[6]=(short)f2bf(x1.z); fa[7]=(short)f2bf(x1.w);
      acc = __builtin_amdgcn_mfma_f32_16x16x32_bf16(fa, fb[s], acc, 0,0,0);
    }
    // D: col(n within tile)=m16, row(node within tile)=quad*4+r
    #pragma unroll
    for (int r = 0; r < 4; ++r) {
      float p = fast_tanh(acc[r] + b1v) * w2v;
      p += __shfl_xor(p, 1); p += __shfl_xor(p, 2);
      p += __shfl_xor(p, 4); p += __shfl_xor(p, 8);
      const int idx = t0 + quad * 4 + r;
      if (m16 == 0 && idx < L) s_part[wv][idx] = p;
    }
    __syncthreads();   // keep 4 waves lockstep so duplicated row loads stay L1-hot
  }
  __syncthreads();

  // ---- Phase B: softmax stats (b2 cancels exactly under shift-invariance) ----
  float m = -INFINITY;
  for (int i = lane; i < L; i += 64)
    m = fmaxf(m, s_part[0][i] + s_part[1][i] + s_part[2][i] + s_part[3][i]);
  #pragma unroll
  for (int o = 32; o; o >>= 1) m = fmaxf(m, __shfl_xor(m, o));
  __syncthreads();                 // all raw-partial reads done before overwrite

  float d = 0.f;
  for (int i = wv * 64 + lane; i < L; i += 256) {
    float e = __expf(s_part[0][i] + s_part[1][i] + s_part[2][i] + s_part[3][i] - m);
    s_part[0][i] = e;              // disjoint per-thread read-modify-write
    d += e;
  }
  #pragma unroll
  for (int o = 32; o; o >>= 1) d += __shfl_xor(d, o);
  if (lane == 0) s_red[wv] = d;
  __syncthreads();
  const float inv = __builtin_amdgcn_rcpf(s_red[0] + s_red[1] + s_red[2] + s_red[3]);

  // ---- Phase C: pooled = sum_i e_i * ball[i] * inv, 4-way row-split ----
  const int lh = lane >> 5;        // which row of the pair
  const int c4 = lane & 31;        // float4 column
  float4 acc = {0.f, 0.f, 0.f, 0.f};
  #pragma unroll 4
  for (int i = start + wv * 2; i + 1 < end; i += 8) {
    const int   row = i + lh;
    const float w   = s_part[0][row - start];
    const float4 v  = ((const float4*)(ball + (size_t)row * HID))[c4];
    acc.x = fmaf(w, v.x, acc.x);
    acc.y = fmaf(w, v.y, acc.y);
    acc.z = fmaf(w, v.z, acc.z);
    acc.w = fmaf(w, v.w, acc.w);
  }
  if ((L & 1) && wv == 0 && lh == 0) {        // odd tail row
    const int   row = end - 1;
    const float w   = s_part[0][row - start];
    const float4 v  = ((const float4*)(ball + (size_t)row * HID))[c4];
    acc.x = fmaf(w, v.x, acc.x);
    acc.y = fmaf(w, v.y, acc.y);
    acc.z = fmaf(w, v.z, acc.z);
    acc.w = fmaf(w, v.w, acc.w);
  }
  acc.x += __shfl_xor(acc.x, 32);
  acc.y += __shfl_xor(acc.y, 32);
  acc.z += __shfl_xor(acc.z, 32);
  acc.w += __shfl_xor(acc.w, 32);
  if (wv != 0) { if (lh == 0) s_red4[wv - 1][c4] = acc; }
  __syncthreads();
  if (wv == 0 && lh == 0) {
    const float4 a1 = s_red4[0][c4], a2 = s_red4[1][c4], a3 = s_red4[2][c4];
    float4 o;
    o.x = (acc.x + a1.x + a2.x + a3.x) * inv;
    o.y = (acc.y + a1.y + a2.y + a3.y) * inv;
    o.z = (acc.z + a1.z + a2.z + a3.z) * inv;
    o.w = (acc.w + a1.w + a2.w + a3.w) * inv;
    outp[c4] = o;
  }
}

// K3: h = [query|pooled]@comb_w + comb_b -> LN -> GELU(exact) -> two heads.
__global__ __launch_bounds__(128) void k_combine(
    const float* __restrict__ query, const float* __restrict__ pooled,
    const float* __restrict__ cw, const float* __restrict__ cb,
    const float* __restrict__ lg, const float* __restrict__ lb,
    const float* __restrict__ bw1, const float* __restrict__ bb1,
    const float* __restrict__ bw2, const float* __restrict__ bb2,
    const float* __restrict__ ww1, const float* __restrict__ wb1,
    const float* __restrict__ ww2, const float* __restrict__ wb2,
    float* __restrict__ out)
{
  __shared__ float in_lds[256][8];
  __shared__ float h_lds[128][8];
  __shared__ float part[2][2][8];
  const int tid  = threadIdx.x;
  const int row0 = blockIdx.x * 8;

  for (int idx = tid; idx < 2048; idx += 128) {
    const int k = idx >> 3, r = idx & 7;
    float v = (k < 128) ? query[(size_t)(row0 + r) * 128 + k]
                        : pooled[(size_t)(row0 + r) * 128 + (k - 128)];
    in_lds[k][r] = v;
  }
  __syncthreads();

  const int j = tid;
  float acc[8];
  const float cbj = cb[j];
  #pragma unroll
  for (int r = 0; r < 8; ++r) acc[r] = cbj;
  for (int k = 0; k < 256; ++k) {
    const float w = cw[k * 128 + j];
    #pragma unroll
    for (int r = 0; r < 8; ++r) acc[r] = fmaf(in_lds[k][r], w, acc[r]);
  }

  const int wv = tid >> 6, ln = tid & 63;
  #pragma unroll
  for (int r = 0; r < 8; ++r) {
    float v = acc[r], v2 = v * v;
    #pragma unroll
    for (int o = 32; o; o >>= 1) { v += __shfl_xor(v, o); v2 += __shfl_xor(v2, o); }
    if (ln == 0) { part[0][wv][r] = v; part[1][wv][r] = v2; }
  }
  __syncthreads();
  const float gj = lg[j], bj = lb[j];
  #pragma unroll
  for (int r = 0; r < 8; ++r) {
    const float S = part[0][0][r] + part[0][1][r];
    const float Q = part[1][0][r] + part[1][1][r];
    const float mean = S * (1.f / 128.f);
    const float var  = Q * (1.f / 128.f) - mean * mean;
    const float rs   = rsqrtf(var + 1e-5f);
    float x = (acc[r] - mean) * rs * gj + bj;
    x = 0.5f * x * (1.f + erff(x * 0.70710678118654752f));   // exact GELU
    h_lds[j][r] = x;
  }
  __syncthreads();

  const float* W1 = wv ? ww1 : bw1;
  const float* B1 = wv ? wb1 : bb1;
  const float* W2 = wv ? ww2 : bw2;
  const float  B2 = wv ? wb2[0] : bb2[0];
  float t[8];
  const float b1l = B1[ln];
  #pragma unroll
  for (int r = 0; r < 8; ++r) t[r] = b1l;
  for (int k = 0; k < 128; ++k) {
    const float w = W1[k * 64 + ln];
    #pragma unroll
    for (int r = 0; r < 8; ++r) t[r] = fmaf(h_lds[k][r], w, t[r]);
  }
  const float w2l = W2[ln];
  #pragma unroll
  for (int r = 0; r < 8; ++r) {
    float o = fmaxf(t[r], 0.f) * w2l;
    #pragma unroll
    for (int m = 32; m; m >>= 1) o += __shfl_xor(o, m);
    if (ln == 0) out[wv * BATCH + row0 + r] = o + B2;
  }
}

extern "C" void kernel_launch(void* const* d_in, const int* in_sizes, int n_in,
                              void* d_out, int out_size, void* d_ws, size_t ws_size,
                              hipStream_t stream)
{
  const float* query = (const float*)d_in[0];
  const float* ball  = (const float*)d_in[1];
  const int*   bb    = (const int*)  d_in[2];
  const float* aw1   = (const float*)d_in[3];
  const float* ab1   = (const float*)d_in[4];
  const float* aw2   = (const float*)d_in[5];
  const float* ab2   = (const float*)d_in[6];
  const float* cw    = (const float*)d_in[7];
  const float* cb    = (const float*)d_in[8];
  const float* lg    = (const float*)d_in[9];
  const float* lbeta = (const float*)d_in[10];
  const float* bw1   = (const float*)d_in[11];
  const float* bb1   = (const float*)d_in[12];
  const float* bw2   = (const float*)d_in[13];
  const float* bb2   = (const float*)d_in[14];
  const float* ww1   = (const float*)d_in[15];
  const float* wb1   = (const float*)d_in[16];
  const float* ww2   = (const float*)d_in[17];
  const float* wb2   = (const float*)d_in[18];

  float* pooled = (float*)d_ws;                    // B*H floats
  int*   rs     = (int*)(pooled + (size_t)BATCH * HID);  // B+1 ints
  float* out    = (float*)d_out;

  k_bounds<<<(N_NODES + 255) / 256, 256, 0, stream>>>(bb, rs);
  k_score_pool<<<BATCH, 256, 0, stream>>>(ball, rs, aw1, ab1, aw2, ab2, pooled);
  k_combine<<<BATCH / 8, 128, 0, stream>>>(query, pooled, cw, cb, lg, lbeta,
                                           bw1, bb1, bw2, bb2, ww1, wb1, ww2, wb2, out);
}

// Round 3
// 481.551 us; speedup vs baseline: 1.0137x; 1.0137x over previous
//
#include <hip/hip_runtime.h>
#include <math.h>

#define N_NODES 524288
#define BATCH   4096
#define HID     128
#define CH      32     // chunk rows per online-softmax step

typedef __attribute__((ext_vector_type(8))) short bf16x8;
typedef __attribute__((ext_vector_type(4))) float f32x4;

__device__ __forceinline__ unsigned short f2bf(float f) {
  unsigned int u = __float_as_uint(f);
  u = (u + 0x7FFFu + ((u >> 16) & 1u)) >> 16;   // RNE
  return (unsigned short)u;
}

__device__ __forceinline__ float fast_tanh(float x) {
  float cx = fminf(fmaxf(x, -9.f), 9.f);
  float e  = __expf(2.f * cx);
  return (e - 1.f) * __builtin_amdgcn_rcpf(e + 1.f);
}

// logical (row,col) -> physical float index in a swizzled [CH][HID] LDS tile.
// 16B granule index (col>>2) XORed with (row&7): conflict-free b128/b64 reads.
#define SWZ(row, col) (((row) * HID) + ((((col) >> 2) ^ ((row) & 7)) << 2) + ((col) & 3))

// K0: segment boundaries from sorted ball_batch
__global__ __launch_bounds__(256) void k_bounds(const int* __restrict__ bb,
                                                int* __restrict__ rs)
{
  const int i = blockIdx.x * 256 + threadIdx.x;
  if (i >= N_NODES) return;
  const int cur  = bb[i];
  const int prev = (i == 0) ? -1 : bb[i - 1];
  for (int b = prev + 1; b <= cur; ++b) rs[b] = i;
  if (i == N_NODES - 1)
    for (int b = cur + 1; b <= BATCH; ++b) rs[b] = N_NODES;
}

// K1: single-pass fused scores -> online softmax -> pooling. ball read ONCE.
// 4 waves/block; chunk staged coalesced into swizzled LDS (double-buffered,
// register-prefetched); scores via n-split bf16 MFMA from LDS; pooling from LDS.
__global__ __launch_bounds__(256) void k_score_pool(
    const float* __restrict__ ball, const int* __restrict__ rs,
    const float* __restrict__ w1, const float* __restrict__ b1,
    const float* __restrict__ w2, const float* __restrict__ b2,
    float* __restrict__ pooled)
{
  __shared__ __align__(16) float buf[2][CH * HID];   // 2 x 16 KB
  __shared__ float s_part[4][CH];
  __shared__ float s_red[4];
  __shared__ float s_obuf[3][HID];

  const int tid  = threadIdx.x;
  const int lane = tid & 63;
  const int wv   = tid >> 6;       // wave = n-tile 0..3
  const int m16  = lane & 15;
  const int quad = lane >> 4;
  const int b    = blockIdx.x;

  const int start = rs[b];
  const int end   = rs[b + 1];
  const int L     = end - start;

  float2* outp = (float2*)(pooled + (size_t)b * HID);
  if (L <= 0) { if (tid < 64) outp[tid] = make_float2(0.f, 0.f); return; }

  // W1 fragment for this wave's n-tile: n = wv*16+m16, k = s*32 + quad*8 + j
  bf16x8 fb[4];
  const int n = wv * 16 + m16;
  #pragma unroll
  for (int s = 0; s < 4; ++s) {
    const int k0 = s * 32 + quad * 8;
    bf16x8 v;
    #pragma unroll
    for (int j = 0; j < 8; ++j) v[j] = (short)f2bf(w1[(k0 + j) * 64 + n]);
    fb[s] = v;
  }
  const float b1v = b1[n], w2v = w2[n];

  const int nc = (L + CH - 1) / CH;
  float4 pre[4];

  // --- prologue: stage chunk 0 ---
  #pragma unroll
  for (int rnd = 0; rnd < 4; ++rnd) {
    const int f = rnd * 1024 + tid * 4;
    const int row = f >> 7, col = f & 127;
    int gr = start + row; if (gr >= end) gr = end - 1;
    pre[rnd] = *(const float4*)(ball + (size_t)gr * HID + col);
  }
  #pragma unroll
  for (int rnd = 0; rnd < 4; ++rnd) {
    const int f = rnd * 1024 + tid * 4;
    const int row = f >> 7, col = f & 127;
    *(float4*)&buf[0][SWZ(row, col)] = pre[rnd];
  }
  __syncthreads();

  float  m_run = -INFINITY, d_run = 0.f;
  float2 O = make_float2(0.f, 0.f);
  int p = 0;

  for (int c = 0; c < nc; ++c) {
    const int Lc = min(CH, L - c * CH);

    // prefetch chunk c+1 into registers (latency hides under MFMA below)
    if (c + 1 < nc) {
      #pragma unroll
      for (int rnd = 0; rnd < 4; ++rnd) {
        const int f = rnd * 1024 + tid * 4;
        const int row = f >> 7, col = f & 127;
        int gr = start + (c + 1) * CH + row; if (gr >= end) gr = end - 1;
        pre[rnd] = *(const float4*)(ball + (size_t)gr * HID + col);
      }
    }

    // --- scores for chunk c (n-tile wv), from swizzled LDS ---
    #pragma unroll
    for (int sub = 0; sub < 2; ++sub) {
      const int row = sub * 16 + m16;
      f32x4 acc = {0.f, 0.f, 0.f, 0.f};
      #pragma unroll
      for (int s = 0; s < 4; ++s) {
        const float4 x0 = *(const float4*)&buf[p][SWZ(row, s * 32 + quad * 8)];
        const float4 x1 = *(const float4*)&buf[p][SWZ(row, s * 32 + quad * 8 + 4)];
        bf16x8 fa;
        fa[0]=(short)f2bf(x0.x); fa[1]=(short)f2bf(x0.y);
        fa[2]=(short)f2bf(x0.z); fa[3]=(short)f2bf(x0.w);
        fa[4]=(short)f2bf(x1.x); fa[5]=(short)f2bf(x1.y);
        fa[6]=(short)f2bf(x1.z); fa[7]=(short)f2bf(x1.w);
        acc = __builtin_amdgcn_mfma_f32_16x16x32_bf16(fa, fb[s], acc, 0,0,0);
      }
      #pragma unroll
      for (int r = 0; r < 4; ++r) {
        float sc = fast_tanh(acc[r] + b1v) * w2v;
        sc += __shfl_xor(sc, 1); sc += __shfl_xor(sc, 2);
        sc += __shfl_xor(sc, 4); sc += __shfl_xor(sc, 8);
        if (m16 == 0) s_part[wv][sub * 16 + quad * 4 + r] = sc;
      }
    }
    __syncthreads();

    // --- online-softmax stats: lane i holds row i's score (i < Lc) ---
    const float sv = (lane < Lc)
        ? (s_part[0][lane] + s_part[1][lane] + s_part[2][lane] + s_part[3][lane])
        : -INFINITY;
    float mc = sv;
    #pragma unroll
    for (int o = 32; o; o >>= 1) mc = fmaxf(mc, __shfl_xor(mc, o));
    const float m_new = fmaxf(m_run, mc);
    const float scale = __expf(m_run - m_new);      // first chunk: exp(-inf)=0
    d_run *= scale; O.x *= scale; O.y *= scale;
    m_run = m_new;

    // --- write prefetched chunk c+1 into the other buffer ---
    if (c + 1 < nc) {
      #pragma unroll
      for (int rnd = 0; rnd < 4; ++rnd) {
        const int f = rnd * 1024 + tid * 4;
        const int row = f >> 7, col = f & 127;
        *(float4*)&buf[p ^ 1][SWZ(row, col)] = pre[rnd];
      }
    }

    // --- pooling from LDS: wave wv owns rows wv, wv+4, ... (cols 2*lane,+1) ---
    for (int r = wv; r < Lc; r += 4) {
      const float e = __expf(__shfl(sv, r) - m_new);
      const float2 v = *(const float2*)
          &buf[p][r * HID + (((lane >> 1) ^ (r & 7)) << 2) + (lane & 1) * 2];
      O.x = fmaf(e, v.x, O.x);
      O.y = fmaf(e, v.y, O.y);
      d_run += e;
    }
    __syncthreads();
    p ^= 1;
  }

  // --- epilogue: combine 4 wave partials, normalize, store ---
  if (wv) { s_obuf[wv - 1][lane * 2] = O.x; s_obuf[wv - 1][lane * 2 + 1] = O.y; }
  if (lane == 0) s_red[wv] = d_run;
  __syncthreads();
  if (wv == 0) {
    const float inv = 1.f / (s_red[0] + s_red[1] + s_red[2] + s_red[3]);
    float2 o;
    o.x = (O.x + s_obuf[0][lane*2]   + s_obuf[1][lane*2]   + s_obuf[2][lane*2])   * inv;
    o.y = (O.y + s_obuf[0][lane*2+1] + s_obuf[1][lane*2+1] + s_obuf[2][lane*2+1]) * inv;
    outp[lane] = o;
  }
}

// K3: h = [query|pooled]@comb_w + comb_b -> LN -> GELU(exact) -> two heads.
__global__ __launch_bounds__(128) void k_combine(
    const float* __restrict__ query, const float* __restrict__ pooled,
    const float* __restrict__ cw, const float* __restrict__ cb,
    const float* __restrict__ lg, const float* __restrict__ lb,
    const float* __restrict__ bw1, const float* __restrict__ bb1,
    const float* __restrict__ bw2, const float* __restrict__ bb2,
    const float* __restrict__ ww1, const float* __restrict__ wb1,
    const float* __restrict__ ww2, const float* __restrict__ wb2,
    float* __restrict__ out)
{
  __shared__ float in_lds[256][8];
  __shared__ float h_lds[128][8];
  __shared__ float part[2][2][8];
  const int tid  = threadIdx.x;
  const int row0 = blockIdx.x * 8;

  for (int idx = tid; idx < 2048; idx += 128) {
    const int k = idx >> 3, r = idx & 7;
    float v = (k < 128) ? query[(size_t)(row0 + r) * 128 + k]
                        : pooled[(size_t)(row0 + r) * 128 + (k - 128)];
    in_lds[k][r] = v;
  }
  __syncthreads();

  const int j = tid;
  float acc[8];
  const float cbj = cb[j];
  #pragma unroll
  for (int r = 0; r < 8; ++r) acc[r] = cbj;
  for (int k = 0; k < 256; ++k) {
    const float w = cw[k * 128 + j];
    #pragma unroll
    for (int r = 0; r < 8; ++r) acc[r] = fmaf(in_lds[k][r], w, acc[r]);
  }

  const int wv = tid >> 6, ln = tid & 63;
  #pragma unroll
  for (int r = 0; r < 8; ++r) {
    float v = acc[r], v2 = v * v;
    #pragma unroll
    for (int o = 32; o; o >>= 1) { v += __shfl_xor(v, o); v2 += __shfl_xor(v2, o); }
    if (ln == 0) { part[0][wv][r] = v; part[1][wv][r] = v2; }
  }
  __syncthreads();
  const float gj = lg[j], bj = lb[j];
  #pragma unroll
  for (int r = 0; r < 8; ++r) {
    const float S = part[0][0][r] + part[0][1][r];
    const float Q = part[1][0][r] + part[1][1][r];
    const float mean = S * (1.f / 128.f);
    const float var  = Q * (1.f / 128.f) - mean * mean;
    const float rsd  = rsqrtf(var + 1e-5f);
    float x = (acc[r] - mean) * rsd * gj + bj;
    x = 0.5f * x * (1.f + erff(x * 0.70710678118654752f));   // exact GELU
    h_lds[j][r] = x;
  }
  __syncthreads();

  const float* W1 = wv ? ww1 : bw1;
  const float* B1 = wv ? wb1 : bb1;
  const float* W2 = wv ? ww2 : bw2;
  const float  B2 = wv ? wb2[0] : bb2[0];
  float t[8];
  const float b1l = B1[ln];
  #pragma unroll
  for (int r = 0; r < 8; ++r) t[r] = b1l;
  for (int k = 0; k < 128; ++k) {
    const float w = W1[k * 64 + ln];
    #pragma unroll
    for (int r = 0; r < 8; ++r) t[r] = fmaf(h_lds[k][r], w, t[r]);
  }
  const float w2l = W2[ln];
  #pragma unroll
  for (int r = 0; r < 8; ++r) {
    float o = fmaxf(t[r], 0.f) * w2l;
    #pragma unroll
    for (int m = 32; m; m >>= 1) o += __shfl_xor(o, m);
    if (ln == 0) out[wv * BATCH + row0 + r] = o + B2;
  }
}

extern "C" void kernel_launch(void* const* d_in, const int* in_sizes, int n_in,
                              void* d_out, int out_size, void* d_ws, size_t ws_size,
                              hipStream_t stream)
{
  const float* query = (const float*)d_in[0];
  const float* ball  = (const float*)d_in[1];
  const int*   bb    = (const int*)  d_in[2];
  const float* aw1   = (const float*)d_in[3];
  const float* ab1   = (const float*)d_in[4];
  const float* aw2   = (const float*)d_in[5];
  const float* ab2   = (const float*)d_in[6];
  const float* cw    = (const float*)d_in[7];
  const float* cb    = (const float*)d_in[8];
  const float* lg    = (const float*)d_in[9];
  const float* lbeta = (const float*)d_in[10];
  const float* bw1   = (const float*)d_in[11];
  const float* bb1   = (const float*)d_in[12];
  const float* bw2   = (const float*)d_in[13];
  const float* bb2   = (const float*)d_in[14];
  const float* ww1   = (const float*)d_in[15];
  const float* wb1   = (const float*)d_in[16];
  const float* ww2   = (const float*)d_in[17];
  const float* wb2   = (const float*)d_in[18];

  float* pooled = (float*)d_ws;                          // B*H floats
  int*   rs     = (int*)(pooled + (size_t)BATCH * HID);  // B+1 ints
  float* out    = (float*)d_out;

  k_bounds<<<(N_NODES + 255) / 256, 256, 0, stream>>>(bb, rs);
  k_score_pool<<<BATCH, 256, 0, stream>>>(ball, rs, aw1, ab1, aw2, ab2, pooled);
  k_combine<<<BATCH / 8, 128, 0, stream>>>(query, pooled, cw, cb, lg, lbeta,
                                           bw1, bb1, bw2, bb2, ww1, wb1, ww2, wb2, out);
}